// Round 1
// 477.816 us; speedup vs baseline: 1.0346x; 1.0346x over previous
//
#include <hip/hip_runtime.h>

#define NSAMP 1024
#define NC 21
#define NFG 20
#define HW 1681
#define MIN_PROB 1e-4f
#define INV_NORM (1.0f/1.0021f)   // 1 / (1 + 21*MIN_PROB)

// log-scale histogram for kernelB: bin = (float_bits >> 16) - BIN_BASE
// exponent(8 bits) + 7 mantissa bits -> 0.78% bin width.
// p in [9.98e-5, 0.998] -> exponent field 113..126; base at 111 gives margin.
#define NB 2048
#define BPT 8                     // bins per thread (256 threads)
#define BIN_BASE (111 << 7)       // 14208
#define L2Q_FG (-0.0057823528f)   // log2(0.996)
#define L2Q_BG (-0.0014434217f)   // log2(0.999)
#define NITB 7                    // ceil(HW/256) load batches in kernelB

__device__ __forceinline__ float waveSum(float v) {
    #pragma unroll
    for (int o = 32; o > 0; o >>= 1) v += __shfl_down(v, o);
    return v;
}
__device__ __forceinline__ float waveMax(float v) {
    #pragma unroll
    for (int o = 32; o > 0; o >>= 1) v = fmaxf(v, __shfl_down(v, o));
    return v;
}

// Kernel A v2: batch ALL 63 strided loads (outp/gt/crf x 21 channels) into
// registers BEFORE any compute. Previous version (28 VGPR) let the compiler
// issue gt/crf loads one-at-a-time inside the exp/log chain -> ~2 outstanding
// loads/wave -> 1.65 TB/s (26% of achievable). 63 outstanding loads/wave
// = 16 KB in flight per wave; HBM latency fully covered even at the lower
// occupancy (~85 VGPR -> 4 waves/SIMD).
__global__ __launch_bounds__(256) void kernelA(
    const float* __restrict__ outp, const float* __restrict__ gt,
    const float* __restrict__ crf, float* __restrict__ logZ,
    float* __restrict__ samp_s, float* __restrict__ samp_cnt,
    float* __restrict__ crf_acc)
{
    const int n = blockIdx.y;
    const int pix = blockIdx.x * 256 + threadIdx.x;
    const bool act = (pix < HW);

    float a_s = 0.f, a_cnt = 0.f, a_c = 0.f;
    if (act) {
        const size_t base = (size_t)n * NC * HW + pix;
        const float* po = outp + base;
        const float* pg = gt   + base;
        const float* pc = crf  + base;

        float t[NC], g[NC], cl[NC];
        #pragma unroll
        for (int c = 0; c < NC; ++c) t[c]  = po[(size_t)c * HW];
        #pragma unroll
        for (int c = 0; c < NC; ++c) g[c]  = pg[(size_t)c * HW];
        #pragma unroll
        for (int c = 0; c < NC; ++c) cl[c] = pc[(size_t)c * HW];

        float m = t[0];
        #pragma unroll
        for (int c = 1; c < NC; ++c) m = fmaxf(m, t[c]);
        float S = 0.f;
        #pragma unroll
        for (int c = 0; c < NC; ++c) { t[c] = __expf(t[c] - m); S += t[c]; }
        const float invS = 1.0f / S;
        #pragma unroll
        for (int c = 0; c < NC; ++c) {
            float p  = (t[c] * invS + MIN_PROB) * INV_NORM;
            float lp = __logf(p);
            a_s  += g[c] * lp;
            a_cnt += g[c];
            a_c  += __expf(cl[c]) * (cl[c] - lp);
        }
        logZ[(size_t)n * HW + pix] = m + __logf(S);
    }
    a_s = waveSum(a_s); a_cnt = waveSum(a_cnt); a_c = waveSum(a_c);
    __shared__ float sred[3][4];
    const int lane = threadIdx.x & 63, wid = threadIdx.x >> 6;
    if (lane == 0) { sred[0][wid] = a_s; sred[1][wid] = a_cnt; sred[2][wid] = a_c; }
    __syncthreads();
    if (threadIdx.x == 0) {
        atomicAdd(&samp_s[n],   sred[0][0] + sred[0][1] + sred[0][2] + sred[0][3]);
        atomicAdd(&samp_cnt[n], sred[1][0] + sred[1][1] + sred[1][2] + sred[1][3]);
        atomicAdd(crf_acc,      sred[2][0] + sred[2][1] + sred[2][2] + sred[2][3]);
    }
}

// Kernel B v3: same counting-sort GWRP as v2, but the 7x2 strided global
// loads (ob, lz) are batched into register arrays ahead of the
// exp + LDS-atomic chain (same latency-hiding fix as kernelA).
__global__ __launch_bounds__(256) void kernelB(
    const float* __restrict__ outp, const float* __restrict__ logZ,
    float* __restrict__ pm, float* __restrict__ pmx, float* __restrict__ pbg)
{
    __shared__ unsigned long long s_hist[NB];
    __shared__ int   s_wt[4];
    __shared__ float s_red[8];

    const int tid = threadIdx.x;
    const int n = blockIdx.x / NC;
    const int c = blockIdx.x % NC;
    const int lane = tid & 63, wid = tid >> 6;

    #pragma unroll
    for (int j = 0; j < BPT; ++j) s_hist[tid + j * 256] = 0ULL;

    const float* ob = outp + ((size_t)n * NC + c) * HW;
    const float* lz = logZ + (size_t)n * HW;

    // batched loads (issued before the barrier so they overlap it)
    float ov[NITB], zv[NITB];
    #pragma unroll
    for (int k = 0; k < NITB; ++k) {
        const int i = tid + k * 256;
        if (i < HW) { ov[k] = ob[i]; zv[k] = lz[i]; }
    }
    __syncthreads();

    float maxv = 0.f;
    #pragma unroll
    for (int k = 0; k < NITB; ++k) {
        const int i = tid + k * 256;
        if (i < HW) {
            float p = (__expf(ov[k] - zv[k]) + MIN_PROB) * INV_NORM;
            maxv = fmaxf(maxv, p);
            int b = (int)(__float_as_uint(p) >> 16) - BIN_BASE;
            b = min(max(b, 0), NB - 1);
            unsigned long long pk = (1ULL << 44) |
                (unsigned long long)(p * 4294967296.0f);
            atomicAdd(&s_hist[b], pk);
        }
    }
    __syncthreads();

    // thread tid owns bins NB-1-tid*BPT-j (j=0..BPT-1), i.e. descending value
    // order with increasing tid. Read back, unpack.
    int   cnt[BPT];
    float vs[BPT];
    int cl = 0;
    #pragma unroll
    for (int j = 0; j < BPT; ++j) {
        unsigned long long pk = s_hist[NB - 1 - tid * BPT - j];
        cnt[j] = (int)(pk >> 44);
        vs[j]  = (float)(pk & 0xFFFFFFFFFFFULL) * (1.0f / 4294967296.0f);
        cl += cnt[j];
    }

    // exclusive prefix of cl in tid order = # elements in strictly higher bins
    int incl = cl;
    #pragma unroll
    for (int o = 1; o < 64; o <<= 1) {
        int u = __shfl_up(incl, o);
        if (lane >= o) incl += u;
    }
    if (lane == 63) s_wt[wid] = incl;   // wave total
    __syncthreads();
    int G = incl - cl;
    for (int w = 0; w < 4; ++w) if (w < wid) G += s_wt[w];

    const float l2q = (c == 0) ? L2Q_BG : L2Q_FG;
    float contrib = 0.f;
    #pragma unroll
    for (int j = 0; j < BPT; ++j) {
        int cb = cnt[j];
        if (cb > 0) {
            float qg = exp2f(l2q * (float)G);
            contrib += vs[j] * qg * (1.0f - exp2f(l2q * (float)cb)) / (float)cb;
            G += cb;
        }
    }
    contrib = waveSum(contrib);
    maxv = waveMax(maxv);
    if (lane == 0) { s_red[wid] = contrib; s_red[4 + wid] = maxv; }
    __syncthreads();
    if (tid == 0) {
        float total = s_red[0] + s_red[1] + s_red[2] + s_red[3];
        float mx = fmaxf(fmaxf(s_red[4], s_red[5]), fmaxf(s_red[6], s_red[7]));
        float denom = 1.0f - exp2f(l2q * (float)HW);   // sum(w) * (1-q)
        float mean = total / denom;
        if (c == 0) pbg[n] = mean;
        else { pm[(size_t)n * NFG + (c - 1)] = mean; pmx[(size_t)n * NFG + (c - 1)] = mx; }
    }
}

// Kernel C: final assembly over 1024 samples -> scalar loss.
__global__ __launch_bounds__(256) void kernelC(
    const float* __restrict__ label, const float* __restrict__ samp_s,
    const float* __restrict__ samp_cnt, const float* __restrict__ pm,
    const float* __restrict__ pmx, const float* __restrict__ pbg,
    const float* __restrict__ crf_acc, float* __restrict__ out)
{
    const int tid = threadIdx.x;
    float acc = 0.f;
    for (int n = tid; n < NSAMP; n += 256) {
        float v = samp_s[n] / samp_cnt[n];
        float s_stat = 0.f, l1 = 0.f, l2 = 0.f;
        #pragma unroll
        for (int c = 0; c < NFG; ++c) {
            float st = (label[(size_t)n * NC + 1 + c] > 0.5f) ? 1.0f : 0.0f;
            s_stat += st;
            l1 += st * __logf(pm[(size_t)n * NFG + c]);
            l2 += (1.0f - st) * __logf(1.0f - pmx[(size_t)n * NFG + c]);
        }
        acc += v + l1 / s_stat + l2 / ((float)NFG - s_stat) + __logf(pbg[n]);
    }
    acc = waveSum(acc);
    __shared__ float s_red[4];
    const int lane = tid & 63, wid = tid >> 6;
    if (lane == 0) s_red[wid] = acc;
    __syncthreads();
    if (tid == 0) {
        float tot = s_red[0] + s_red[1] + s_red[2] + s_red[3];
        out[0] = -(tot / (float)NSAMP) + crf_acc[0] / ((float)NSAMP * (float)HW);
    }
}

extern "C" void kernel_launch(void* const* d_in, const int* in_sizes, int n_in,
                              void* d_out, int out_size, void* d_ws, size_t ws_size,
                              hipStream_t stream)
{
    const float* outp  = (const float*)d_in[0];
    const float* gt    = (const float*)d_in[1];
    const float* label = (const float*)d_in[2];
    const float* crf   = (const float*)d_in[3];
    float* out = (float*)d_out;

    float* ws = (float*)d_ws;
    float* samp_s   = ws;                  // 1024
    float* samp_cnt = ws + 1024;           // 1024
    float* crf_acc  = ws + 2048;           // 1 (+pad to 2064)
    float* pm   = ws + 2064;               // 1024*20
    float* pmx  = pm + NSAMP * NFG;        // 1024*20
    float* pbg  = pmx + NSAMP * NFG;       // 1024
    float* logZ = pbg + NSAMP;             // 1024*1681  (~6.9 MB total ws use)

    hipMemsetAsync(d_ws, 0, 2064 * sizeof(float), stream);

    dim3 gridA((HW + 255) / 256, NSAMP);
    kernelA<<<gridA, 256, 0, stream>>>(outp, gt, crf, logZ, samp_s, samp_cnt, crf_acc);
    kernelB<<<NSAMP * NC, 256, 0, stream>>>(outp, logZ, pm, pmx, pbg);
    kernelC<<<1, 256, 0, stream>>>(label, samp_s, samp_cnt, pm, pmx, pbg, crf_acc, out);
}

// Round 2
// 476.283 us; speedup vs baseline: 1.0379x; 1.0032x over previous
//
#include <hip/hip_runtime.h>

#define NSAMP 1024
#define NC 21
#define NFG 20
#define HW 1681
#define NQ4 420                   // full float4 groups per plane (HW = 4*420 + 1)
#define MIN_PROB 1e-4f
#define INV_NORM (1.0f/1.0021f)   // 1 / (1 + 21*MIN_PROB)

// log-scale histogram for kernelB: bin = (float_bits >> 16) - BIN_BASE
// exponent(8 bits) + 7 mantissa bits -> 0.78% bin width.
// p in [9.98e-5, 0.998] -> exponent field 113..126; base at 111 gives margin.
#define NB 2048
#define BPT 8                     // bins per thread (256 threads)
#define BIN_BASE (111 << 7)       // 14208
#define L2Q_FG (-0.0057823528f)   // log2(0.996)
#define L2Q_BG (-0.0014434217f)   // log2(0.999)

typedef float f4_t __attribute__((ext_vector_type(4)));

// 4B-aligned 16B vector load/store: channel stride 1681 floats means rows are
// only dword-aligned. memcpy -> load <4 x float> align 4 -> global_load_dwordx4
// (gfx950 supports unaligned global access).
__device__ __forceinline__ f4_t ld4(const float* p) {
    f4_t v; __builtin_memcpy(&v, p, 16); return v;
}
__device__ __forceinline__ void st4(float* p, f4_t v) {
    __builtin_memcpy(p, &v, 16);
}

__device__ __forceinline__ float waveSum(float v) {
    #pragma unroll
    for (int o = 32; o > 0; o >>= 1) v += __shfl_down(v, o);
    return v;
}
__device__ __forceinline__ float waveMax(float v) {
    #pragma unroll
    for (int o = 32; o > 0; o >>= 1) v = fmaxf(v, __shfl_down(v, o));
    return v;
}

// Kernel A v4: float4 per thread (4 consecutive pixels). 21 dwordx4 in flight
// during the t-phase (21 KB/wave) vs ~9.2 KB/CU needed for peak HBM.
// v3's scalar batching failed (VGPR 60: compiler re-sank per-dword loads);
// dwordx4 makes the sink granularity 16B = 4 consumption iterations per trip.
__global__ __launch_bounds__(256) void kernelA(
    const float* __restrict__ outp, const float* __restrict__ gt,
    const float* __restrict__ crf, float* __restrict__ logZ,
    float* __restrict__ samp_s, float* __restrict__ samp_cnt,
    float* __restrict__ crf_acc)
{
    const int n = blockIdx.y;
    const int q = blockIdx.x * 256 + threadIdx.x;   // float4-group index
    const int p0 = q * 4;

    f4_t as4 = {0.f,0.f,0.f,0.f}, acnt4 = {0.f,0.f,0.f,0.f}, ac4 = {0.f,0.f,0.f,0.f};

    if (q < NQ4) {
        const size_t base = (size_t)n * NC * HW + p0;
        const float* po = outp + base;
        const float* pg = gt   + base;
        const float* pc = crf  + base;

        f4_t tv[NC];
        #pragma unroll
        for (int c = 0; c < NC; ++c) tv[c] = ld4(po + (size_t)c * HW);

        f4_t m = tv[0];
        #pragma unroll
        for (int c = 1; c < NC; ++c) {
            #pragma unroll
            for (int j = 0; j < 4; ++j) m[j] = fmaxf(m[j], tv[c][j]);
        }
        f4_t S = {0.f,0.f,0.f,0.f};
        #pragma unroll
        for (int c = 0; c < NC; ++c) {
            #pragma unroll
            for (int j = 0; j < 4; ++j) { tv[c][j] = __expf(tv[c][j] - m[j]); S[j] += tv[c][j]; }
        }
        f4_t invS;
        #pragma unroll
        for (int j = 0; j < 4; ++j) invS[j] = 1.0f / S[j];

        // gt/crf consumption, software-pipelined 3 channels deep (dwordx4 pairs)
        f4_t g0 = ld4(pg);                 f4_t h0 = ld4(pc);
        f4_t g1 = ld4(pg + (size_t)HW);    f4_t h1 = ld4(pc + (size_t)HW);
        f4_t g2 = ld4(pg + 2*(size_t)HW);  f4_t h2 = ld4(pc + 2*(size_t)HW);
        #pragma unroll
        for (int c = 0; c < NC; ++c) {
            f4_t g = g0, h = h0;
            g0 = g1; h0 = h1; g1 = g2; h1 = h2;
            if (c + 3 < NC) {
                g2 = ld4(pg + (size_t)(c+3) * HW);
                h2 = ld4(pc + (size_t)(c+3) * HW);
            }
            #pragma unroll
            for (int j = 0; j < 4; ++j) {
                float p  = (tv[c][j] * invS[j] + MIN_PROB) * INV_NORM;
                float lp = __logf(p);
                as4[j]   += g[j] * lp;
                acnt4[j] += g[j];
                ac4[j]   += __expf(h[j]) * (h[j] - lp);
            }
        }
        f4_t zf;
        #pragma unroll
        for (int j = 0; j < 4; ++j) zf[j] = m[j] + __logf(S[j]);
        st4(logZ + (size_t)n * HW + p0, zf);
    } else if (p0 < HW) {
        // tail pixel 1680 (q == NQ4), scalar path
        const size_t base = (size_t)n * NC * HW + p0;
        float t[NC];
        float m = -3.0e38f;
        #pragma unroll
        for (int c = 0; c < NC; ++c) { t[c] = outp[base + (size_t)c * HW]; m = fmaxf(m, t[c]); }
        float S = 0.f;
        #pragma unroll
        for (int c = 0; c < NC; ++c) { t[c] = __expf(t[c] - m); S += t[c]; }
        const float invS = 1.0f / S;
        #pragma unroll
        for (int c = 0; c < NC; ++c) {
            float p  = (t[c] * invS + MIN_PROB) * INV_NORM;
            float lp = __logf(p);
            float g  = gt[base + (size_t)c * HW];
            as4[0]   += g * lp;
            acnt4[0] += g;
            float h  = crf[base + (size_t)c * HW];
            ac4[0]   += __expf(h) * (h - lp);
        }
        logZ[(size_t)n * HW + p0] = m + __logf(S);
    }

    float a_s   = (as4[0]   + as4[1])   + (as4[2]   + as4[3]);
    float a_cnt = (acnt4[0] + acnt4[1]) + (acnt4[2] + acnt4[3]);
    float a_c   = (ac4[0]   + ac4[1])   + (ac4[2]   + ac4[3]);

    a_s = waveSum(a_s); a_cnt = waveSum(a_cnt); a_c = waveSum(a_c);
    __shared__ float sred[3][4];
    const int lane = threadIdx.x & 63, wid = threadIdx.x >> 6;
    if (lane == 0) { sred[0][wid] = a_s; sred[1][wid] = a_cnt; sred[2][wid] = a_c; }
    __syncthreads();
    if (threadIdx.x == 0) {
        atomicAdd(&samp_s[n],   sred[0][0] + sred[0][1] + sred[0][2] + sred[0][3]);
        atomicAdd(&samp_cnt[n], sred[1][0] + sred[1][1] + sred[1][2] + sred[1][3]);
        atomicAdd(crf_acc,      sred[2][0] + sred[2][1] + sred[2][2] + sred[2][3]);
    }
}

// Kernel B v4: counting-sort GWRP; ob/lz rows are contiguous -> dwordx4 loads
// (2 per stream per thread), batched before the histogram barrier.
__global__ __launch_bounds__(256) void kernelB(
    const float* __restrict__ outp, const float* __restrict__ logZ,
    float* __restrict__ pm, float* __restrict__ pmx, float* __restrict__ pbg)
{
    __shared__ unsigned long long s_hist[NB];
    __shared__ int   s_wt[4];
    __shared__ float s_red[8];

    const int tid = threadIdx.x;
    const int n = blockIdx.x / NC;
    const int c = blockIdx.x % NC;
    const int lane = tid & 63, wid = tid >> 6;

    #pragma unroll
    for (int j = 0; j < BPT; ++j) s_hist[tid + j * 256] = 0ULL;

    const float* ob = outp + ((size_t)n * NC + c) * HW;
    const float* lz = logZ + (size_t)n * HW;

    // batched vector loads (before the barrier so they overlap it)
    const int i40 = tid;            // always < NQ4
    const int i41 = tid + 256;
    const bool f1 = (i41 < NQ4);
    const bool ft = (i41 == NQ4);   // tail element 1680
    f4_t ov0 = ld4(ob + (size_t)i40 * 4);
    f4_t zv0 = ld4(lz + (size_t)i40 * 4);
    f4_t ov1 = {0.f,0.f,0.f,0.f}, zv1 = {0.f,0.f,0.f,0.f};
    float otail = 0.f, ztail = 0.f;
    if (f1) { ov1 = ld4(ob + (size_t)i41 * 4); zv1 = ld4(lz + (size_t)i41 * 4); }
    if (ft) { otail = ob[HW - 1]; ztail = lz[HW - 1]; }
    __syncthreads();

    float maxv = 0.f;
    #pragma unroll
    for (int j = 0; j < 4; ++j) {
        float p = (__expf(ov0[j] - zv0[j]) + MIN_PROB) * INV_NORM;
        maxv = fmaxf(maxv, p);
        int b = (int)(__float_as_uint(p) >> 16) - BIN_BASE;
        b = min(max(b, 0), NB - 1);
        atomicAdd(&s_hist[b], (1ULL << 44) |
                  (unsigned long long)(p * 4294967296.0f));
    }
    if (f1) {
        #pragma unroll
        for (int j = 0; j < 4; ++j) {
            float p = (__expf(ov1[j] - zv1[j]) + MIN_PROB) * INV_NORM;
            maxv = fmaxf(maxv, p);
            int b = (int)(__float_as_uint(p) >> 16) - BIN_BASE;
            b = min(max(b, 0), NB - 1);
            atomicAdd(&s_hist[b], (1ULL << 44) |
                      (unsigned long long)(p * 4294967296.0f));
        }
    }
    if (ft) {
        float p = (__expf(otail - ztail) + MIN_PROB) * INV_NORM;
        maxv = fmaxf(maxv, p);
        int b = (int)(__float_as_uint(p) >> 16) - BIN_BASE;
        b = min(max(b, 0), NB - 1);
        atomicAdd(&s_hist[b], (1ULL << 44) |
                  (unsigned long long)(p * 4294967296.0f));
    }
    __syncthreads();

    // thread tid owns bins NB-1-tid*BPT-j (j=0..BPT-1), i.e. descending value
    // order with increasing tid. Read back, unpack.
    int   cnt[BPT];
    float vs[BPT];
    int cl = 0;
    #pragma unroll
    for (int j = 0; j < BPT; ++j) {
        unsigned long long pk = s_hist[NB - 1 - tid * BPT - j];
        cnt[j] = (int)(pk >> 44);
        vs[j]  = (float)(pk & 0xFFFFFFFFFFFULL) * (1.0f / 4294967296.0f);
        cl += cnt[j];
    }

    // exclusive prefix of cl in tid order = # elements in strictly higher bins
    int incl = cl;
    #pragma unroll
    for (int o = 1; o < 64; o <<= 1) {
        int u = __shfl_up(incl, o);
        if (lane >= o) incl += u;
    }
    if (lane == 63) s_wt[wid] = incl;   // wave total
    __syncthreads();
    int G = incl - cl;
    for (int w = 0; w < 4; ++w) if (w < wid) G += s_wt[w];

    const float l2q = (c == 0) ? L2Q_BG : L2Q_FG;
    float contrib = 0.f;
    #pragma unroll
    for (int j = 0; j < BPT; ++j) {
        int cb = cnt[j];
        if (cb > 0) {
            float qg = exp2f(l2q * (float)G);
            contrib += vs[j] * qg * (1.0f - exp2f(l2q * (float)cb)) / (float)cb;
            G += cb;
        }
    }
    contrib = waveSum(contrib);
    maxv = waveMax(maxv);
    if (lane == 0) { s_red[wid] = contrib; s_red[4 + wid] = maxv; }
    __syncthreads();
    if (tid == 0) {
        float total = s_red[0] + s_red[1] + s_red[2] + s_red[3];
        float mx = fmaxf(fmaxf(s_red[4], s_red[5]), fmaxf(s_red[6], s_red[7]));
        float denom = 1.0f - exp2f(l2q * (float)HW);   // sum(w) * (1-q)
        float mean = total / denom;
        if (c == 0) pbg[n] = mean;
        else { pm[(size_t)n * NFG + (c - 1)] = mean; pmx[(size_t)n * NFG + (c - 1)] = mx; }
    }
}

// Kernel C: final assembly over 1024 samples -> scalar loss.
__global__ __launch_bounds__(256) void kernelC(
    const float* __restrict__ label, const float* __restrict__ samp_s,
    const float* __restrict__ samp_cnt, const float* __restrict__ pm,
    const float* __restrict__ pmx, const float* __restrict__ pbg,
    const float* __restrict__ crf_acc, float* __restrict__ out)
{
    const int tid = threadIdx.x;
    float acc = 0.f;
    for (int n = tid; n < NSAMP; n += 256) {
        float v = samp_s[n] / samp_cnt[n];
        float s_stat = 0.f, l1 = 0.f, l2 = 0.f;
        #pragma unroll
        for (int c = 0; c < NFG; ++c) {
            float st = (label[(size_t)n * NC + 1 + c] > 0.5f) ? 1.0f : 0.0f;
            s_stat += st;
            l1 += st * __logf(pm[(size_t)n * NFG + c]);
            l2 += (1.0f - st) * __logf(1.0f - pmx[(size_t)n * NFG + c]);
        }
        acc += v + l1 / s_stat + l2 / ((float)NFG - s_stat) + __logf(pbg[n]);
    }
    acc = waveSum(acc);
    __shared__ float s_red[4];
    const int lane = tid & 63, wid = tid >> 6;
    if (lane == 0) s_red[wid] = acc;
    __syncthreads();
    if (tid == 0) {
        float tot = s_red[0] + s_red[1] + s_red[2] + s_red[3];
        out[0] = -(tot / (float)NSAMP) + crf_acc[0] / ((float)NSAMP * (float)HW);
    }
}

extern "C" void kernel_launch(void* const* d_in, const int* in_sizes, int n_in,
                              void* d_out, int out_size, void* d_ws, size_t ws_size,
                              hipStream_t stream)
{
    const float* outp  = (const float*)d_in[0];
    const float* gt    = (const float*)d_in[1];
    const float* label = (const float*)d_in[2];
    const float* crf   = (const float*)d_in[3];
    float* out = (float*)d_out;

    float* ws = (float*)d_ws;
    float* samp_s   = ws;                  // 1024
    float* samp_cnt = ws + 1024;           // 1024
    float* crf_acc  = ws + 2048;           // 1 (+pad to 2064)
    float* pm   = ws + 2064;               // 1024*20
    float* pmx  = pm + NSAMP * NFG;        // 1024*20
    float* pbg  = pmx + NSAMP * NFG;       // 1024
    float* logZ = pbg + NSAMP;             // 1024*1681  (~6.9 MB total ws use)

    hipMemsetAsync(d_ws, 0, 2064 * sizeof(float), stream);

    dim3 gridA((NQ4 + 1 + 255) / 256, NSAMP);   // 2 x 1024 blocks, 4 px/thread
    kernelA<<<gridA, 256, 0, stream>>>(outp, gt, crf, logZ, samp_s, samp_cnt, crf_acc);
    kernelB<<<NSAMP * NC, 256, 0, stream>>>(outp, logZ, pm, pmx, pbg);
    kernelC<<<1, 256, 0, stream>>>(label, samp_s, samp_cnt, pm, pmx, pbg, crf_acc, out);
}

// Round 3
// 465.441 us; speedup vs baseline: 1.0621x; 1.0233x over previous
//
#include <hip/hip_runtime.h>

#define NSAMP 1024
#define NC 21
#define NFG 20
#define HW 1681
#define NQ4 420                   // full float4 groups per plane (HW = 4*420 + 1)
#define NQ2 840                   // full float2 groups per plane (HW = 2*840 + 1)
#define MIN_PROB 1e-4f
#define INV_NORM (1.0f/1.0021f)   // 1 / (1 + 21*MIN_PROB)

// log-scale histogram for kernelB: bin = (float_bits >> 16) - BIN_BASE
// exponent(8 bits) + 7 mantissa bits -> 0.78% bin width.
// p in [9.98e-5, 0.998] -> exponent field 113..126; base at 111 gives margin.
#define NB 2048
#define BPT 8                     // bins per thread (256 threads)
#define BIN_BASE (111 << 7)       // 14208
#define L2Q_FG (-0.0057823528f)   // log2(0.996)
#define L2Q_BG (-0.0014434217f)   // log2(0.999)

typedef float f4_t __attribute__((ext_vector_type(4)));
typedef float f2_t __attribute__((ext_vector_type(2)));

// 4B-aligned vector load/store (channel stride 1681 floats = odd, so only
// dword alignment is guaranteed). memcpy -> vector load align 4 ->
// global_load_dwordx2/x4 (gfx950 supports unaligned global access).
__device__ __forceinline__ f4_t ld4(const float* p) {
    f4_t v; __builtin_memcpy(&v, p, 16); return v;
}
__device__ __forceinline__ f2_t ld2(const float* p) {
    f2_t v; __builtin_memcpy(&v, p, 8); return v;
}
__device__ __forceinline__ void st2(float* p, f2_t v) {
    __builtin_memcpy(p, &v, 8);
}

__device__ __forceinline__ float waveSum(float v) {
    #pragma unroll
    for (int o = 32; o > 0; o >>= 1) v += __shfl_down(v, o);
    return v;
}
__device__ __forceinline__ float waveMax(float v) {
    #pragma unroll
    for (int o = 32; o > 0; o >>= 1) v = fmaxf(v, __shfl_down(v, o));
    return v;
}

// Kernel A v5: float2 per thread, ALL 63 loads (outp/gt/crf x 21ch) issued
// before any compute, locked in place by sched_barrier(0).
// v3/v4 failed because the compiler's occupancy heuristic (VGPR 60/76) sank
// the batched loads back into the compute loops -> ~3 KB in flight/CU ->
// 4.8 B/cy/CU delivered (need 10.3). __launch_bounds__(256,2) raises the
// VGPR cap to 256 so 126 data regs + overhead stay live: 31.5 KB in
// flight per wave, 8 waves/CU.
__global__ __launch_bounds__(256, 2) void kernelA(
    const float* __restrict__ outp, const float* __restrict__ gt,
    const float* __restrict__ crf, float* __restrict__ logZ,
    float* __restrict__ samp_s, float* __restrict__ samp_cnt,
    float* __restrict__ crf_acc)
{
    const int n = blockIdx.y;
    const int q = blockIdx.x * 256 + threadIdx.x;   // float2-group index
    const int p0 = q * 2;

    f2_t as2 = {0.f,0.f}, acnt2 = {0.f,0.f}, ac2 = {0.f,0.f};

    if (q < NQ2) {
        const size_t base = (size_t)n * NC * HW + p0;
        const float* po = outp + base;
        const float* pg = gt   + base;
        const float* pc = crf  + base;

        f2_t tv[NC], gv[NC], hv[NC];
        #pragma unroll
        for (int c = 0; c < NC; ++c) tv[c] = ld2(po + (size_t)c * HW);
        #pragma unroll
        for (int c = 0; c < NC; ++c) gv[c] = ld2(pg + (size_t)c * HW);
        #pragma unroll
        for (int c = 0; c < NC; ++c) hv[c] = ld2(pc + (size_t)c * HW);
        // pin: machine scheduler may not sink these loads into the compute
        __builtin_amdgcn_sched_barrier(0);

        f2_t m = tv[0];
        #pragma unroll
        for (int c = 1; c < NC; ++c) {
            m[0] = fmaxf(m[0], tv[c][0]);
            m[1] = fmaxf(m[1], tv[c][1]);
        }
        f2_t S = {0.f,0.f};
        #pragma unroll
        for (int c = 0; c < NC; ++c) {
            #pragma unroll
            for (int j = 0; j < 2; ++j) { tv[c][j] = __expf(tv[c][j] - m[j]); S[j] += tv[c][j]; }
        }
        f2_t invS;
        invS[0] = 1.0f / S[0];
        invS[1] = 1.0f / S[1];

        #pragma unroll
        for (int c = 0; c < NC; ++c) {
            #pragma unroll
            for (int j = 0; j < 2; ++j) {
                float p  = (tv[c][j] * invS[j] + MIN_PROB) * INV_NORM;
                float lp = __logf(p);
                as2[j]   += gv[c][j] * lp;
                acnt2[j] += gv[c][j];
                ac2[j]   += __expf(hv[c][j]) * (hv[c][j] - lp);
            }
        }
        f2_t zf;
        zf[0] = m[0] + __logf(S[0]);
        zf[1] = m[1] + __logf(S[1]);
        st2(logZ + (size_t)n * HW + p0, zf);
    } else if (p0 < HW) {
        // tail pixel 1680 (q == NQ2), scalar path
        const size_t base = (size_t)n * NC * HW + p0;
        float t[NC];
        float m = -3.0e38f;
        #pragma unroll
        for (int c = 0; c < NC; ++c) { t[c] = outp[base + (size_t)c * HW]; m = fmaxf(m, t[c]); }
        float S = 0.f;
        #pragma unroll
        for (int c = 0; c < NC; ++c) { t[c] = __expf(t[c] - m); S += t[c]; }
        const float invS = 1.0f / S;
        #pragma unroll
        for (int c = 0; c < NC; ++c) {
            float p  = (t[c] * invS + MIN_PROB) * INV_NORM;
            float lp = __logf(p);
            float g  = gt[base + (size_t)c * HW];
            as2[0]   += g * lp;
            acnt2[0] += g;
            float h  = crf[base + (size_t)c * HW];
            ac2[0]   += __expf(h) * (h - lp);
        }
        logZ[(size_t)n * HW + p0] = m + __logf(S);
    }

    float a_s   = as2[0]   + as2[1];
    float a_cnt = acnt2[0] + acnt2[1];
    float a_c   = ac2[0]   + ac2[1];

    a_s = waveSum(a_s); a_cnt = waveSum(a_cnt); a_c = waveSum(a_c);
    __shared__ float sred[3][4];
    const int lane = threadIdx.x & 63, wid = threadIdx.x >> 6;
    if (lane == 0) { sred[0][wid] = a_s; sred[1][wid] = a_cnt; sred[2][wid] = a_c; }
    __syncthreads();
    if (threadIdx.x == 0) {
        atomicAdd(&samp_s[n],   sred[0][0] + sred[0][1] + sred[0][2] + sred[0][3]);
        atomicAdd(&samp_cnt[n], sred[1][0] + sred[1][1] + sred[1][2] + sred[1][3]);
        atomicAdd(crf_acc,      sred[2][0] + sred[2][1] + sred[2][2] + sred[2][3]);
    }
}

// Kernel B v4 (unchanged): counting-sort GWRP; ob/lz rows contiguous ->
// dwordx4 loads (2 per stream per thread), batched before the histogram
// barrier. Suspected next bottleneck: same-bin LDS atomic serialization —
// waiting for its counters once kernelA drops below it.
__global__ __launch_bounds__(256) void kernelB(
    const float* __restrict__ outp, const float* __restrict__ logZ,
    float* __restrict__ pm, float* __restrict__ pmx, float* __restrict__ pbg)
{
    __shared__ unsigned long long s_hist[NB];
    __shared__ int   s_wt[4];
    __shared__ float s_red[8];

    const int tid = threadIdx.x;
    const int n = blockIdx.x / NC;
    const int c = blockIdx.x % NC;
    const int lane = tid & 63, wid = tid >> 6;

    #pragma unroll
    for (int j = 0; j < BPT; ++j) s_hist[tid + j * 256] = 0ULL;

    const float* ob = outp + ((size_t)n * NC + c) * HW;
    const float* lz = logZ + (size_t)n * HW;

    // batched vector loads (before the barrier so they overlap it)
    const int i40 = tid;            // always < NQ4
    const int i41 = tid + 256;
    const bool f1 = (i41 < NQ4);
    const bool ft = (i41 == NQ4);   // tail element 1680
    f4_t ov0 = ld4(ob + (size_t)i40 * 4);
    f4_t zv0 = ld4(lz + (size_t)i40 * 4);
    f4_t ov1 = {0.f,0.f,0.f,0.f}, zv1 = {0.f,0.f,0.f,0.f};
    float otail = 0.f, ztail = 0.f;
    if (f1) { ov1 = ld4(ob + (size_t)i41 * 4); zv1 = ld4(lz + (size_t)i41 * 4); }
    if (ft) { otail = ob[HW - 1]; ztail = lz[HW - 1]; }
    __syncthreads();

    float maxv = 0.f;
    #pragma unroll
    for (int j = 0; j < 4; ++j) {
        float p = (__expf(ov0[j] - zv0[j]) + MIN_PROB) * INV_NORM;
        maxv = fmaxf(maxv, p);
        int b = (int)(__float_as_uint(p) >> 16) - BIN_BASE;
        b = min(max(b, 0), NB - 1);
        atomicAdd(&s_hist[b], (1ULL << 44) |
                  (unsigned long long)(p * 4294967296.0f));
    }
    if (f1) {
        #pragma unroll
        for (int j = 0; j < 4; ++j) {
            float p = (__expf(ov1[j] - zv1[j]) + MIN_PROB) * INV_NORM;
            maxv = fmaxf(maxv, p);
            int b = (int)(__float_as_uint(p) >> 16) - BIN_BASE;
            b = min(max(b, 0), NB - 1);
            atomicAdd(&s_hist[b], (1ULL << 44) |
                      (unsigned long long)(p * 4294967296.0f));
        }
    }
    if (ft) {
        float p = (__expf(otail - ztail) + MIN_PROB) * INV_NORM;
        maxv = fmaxf(maxv, p);
        int b = (int)(__float_as_uint(p) >> 16) - BIN_BASE;
        b = min(max(b, 0), NB - 1);
        atomicAdd(&s_hist[b], (1ULL << 44) |
                  (unsigned long long)(p * 4294967296.0f));
    }
    __syncthreads();

    // thread tid owns bins NB-1-tid*BPT-j (j=0..BPT-1), i.e. descending value
    // order with increasing tid. Read back, unpack.
    int   cnt[BPT];
    float vs[BPT];
    int cl = 0;
    #pragma unroll
    for (int j = 0; j < BPT; ++j) {
        unsigned long long pk = s_hist[NB - 1 - tid * BPT - j];
        cnt[j] = (int)(pk >> 44);
        vs[j]  = (float)(pk & 0xFFFFFFFFFFFULL) * (1.0f / 4294967296.0f);
        cl += cnt[j];
    }

    // exclusive prefix of cl in tid order = # elements in strictly higher bins
    int incl = cl;
    #pragma unroll
    for (int o = 1; o < 64; o <<= 1) {
        int u = __shfl_up(incl, o);
        if (lane >= o) incl += u;
    }
    if (lane == 63) s_wt[wid] = incl;   // wave total
    __syncthreads();
    int G = incl - cl;
    for (int w = 0; w < 4; ++w) if (w < wid) G += s_wt[w];

    const float l2q = (c == 0) ? L2Q_BG : L2Q_FG;
    float contrib = 0.f;
    #pragma unroll
    for (int j = 0; j < BPT; ++j) {
        int cb = cnt[j];
        if (cb > 0) {
            float qg = exp2f(l2q * (float)G);
            contrib += vs[j] * qg * (1.0f - exp2f(l2q * (float)cb)) / (float)cb;
            G += cb;
        }
    }
    contrib = waveSum(contrib);
    maxv = waveMax(maxv);
    if (lane == 0) { s_red[wid] = contrib; s_red[4 + wid] = maxv; }
    __syncthreads();
    if (tid == 0) {
        float total = s_red[0] + s_red[1] + s_red[2] + s_red[3];
        float mx = fmaxf(fmaxf(s_red[4], s_red[5]), fmaxf(s_red[6], s_red[7]));
        float denom = 1.0f - exp2f(l2q * (float)HW);   // sum(w) * (1-q)
        float mean = total / denom;
        if (c == 0) pbg[n] = mean;
        else { pm[(size_t)n * NFG + (c - 1)] = mean; pmx[(size_t)n * NFG + (c - 1)] = mx; }
    }
}

// Kernel C: final assembly over 1024 samples -> scalar loss.
__global__ __launch_bounds__(256) void kernelC(
    const float* __restrict__ label, const float* __restrict__ samp_s,
    const float* __restrict__ samp_cnt, const float* __restrict__ pm,
    const float* __restrict__ pmx, const float* __restrict__ pbg,
    const float* __restrict__ crf_acc, float* __restrict__ out)
{
    const int tid = threadIdx.x;
    float acc = 0.f;
    for (int n = tid; n < NSAMP; n += 256) {
        float v = samp_s[n] / samp_cnt[n];
        float s_stat = 0.f, l1 = 0.f, l2 = 0.f;
        #pragma unroll
        for (int c = 0; c < NFG; ++c) {
            float st = (label[(size_t)n * NC + 1 + c] > 0.5f) ? 1.0f : 0.0f;
            s_stat += st;
            l1 += st * __logf(pm[(size_t)n * NFG + c]);
            l2 += (1.0f - st) * __logf(1.0f - pmx[(size_t)n * NFG + c]);
        }
        acc += v + l1 / s_stat + l2 / ((float)NFG - s_stat) + __logf(pbg[n]);
    }
    acc = waveSum(acc);
    __shared__ float s_red[4];
    const int lane = tid & 63, wid = tid >> 6;
    if (lane == 0) s_red[wid] = acc;
    __syncthreads();
    if (tid == 0) {
        float tot = s_red[0] + s_red[1] + s_red[2] + s_red[3];
        out[0] = -(tot / (float)NSAMP) + crf_acc[0] / ((float)NSAMP * (float)HW);
    }
}

extern "C" void kernel_launch(void* const* d_in, const int* in_sizes, int n_in,
                              void* d_out, int out_size, void* d_ws, size_t ws_size,
                              hipStream_t stream)
{
    const float* outp  = (const float*)d_in[0];
    const float* gt    = (const float*)d_in[1];
    const float* label = (const float*)d_in[2];
    const float* crf   = (const float*)d_in[3];
    float* out = (float*)d_out;

    float* ws = (float*)d_ws;
    float* samp_s   = ws;                  // 1024
    float* samp_cnt = ws + 1024;           // 1024
    float* crf_acc  = ws + 2048;           // 1 (+pad to 2064)
    float* pm   = ws + 2064;               // 1024*20
    float* pmx  = pm + NSAMP * NFG;        // 1024*20
    float* pbg  = pmx + NSAMP * NFG;       // 1024
    float* logZ = pbg + NSAMP;             // 1024*1681  (~6.9 MB total ws use)

    hipMemsetAsync(d_ws, 0, 2064 * sizeof(float), stream);

    dim3 gridA((NQ2 + 1 + 255) / 256, NSAMP);   // 4 x 1024 blocks, 2 px/thread
    kernelA<<<gridA, 256, 0, stream>>>(outp, gt, crf, logZ, samp_s, samp_cnt, crf_acc);
    kernelB<<<NSAMP * NC, 256, 0, stream>>>(outp, logZ, pm, pmx, pbg);
    kernelC<<<1, 256, 0, stream>>>(label, samp_s, samp_cnt, pm, pmx, pbg, crf_acc, out);
}